// Round 7
// baseline (107.117 us; speedup 1.0000x reference)
//
#include <hip/hip_runtime.h>

// BSpline evaluation, MI355X.
// t [2048] f32 sorted, c [512,2048] f32, delta [1] i32.
// out = sample_points [S] ++ spline_values [S, DIM]; S=32768, DIM=512.
// B rows have <=4 nonzeros (cols j-3..j, j = knot span), incl. the reference's
// stale-column quirk (col i final degree = min(3, NK-1-i)).
// R7: NO transpose — eval gathers c[dim][j-3..j] directly (4 scalar loads/dim,
// L2/L3-resident, amortized over 8 samples). Separate tiny weights kernel
// (R6 showed fusing it into eval puts the dependent search on the critical
// path: 94->97 regression). Eval wave = 8 samples x half row (1 float4/lane),
// 8192 waves for latency hiding; j/b via uniform (scalar) loads; NT stores.

#define DEG 3

typedef float vfloat4 __attribute__((ext_vector_type(4)));

__device__ __forceinline__ float kn(const float* __restrict__ t, int i) {
    return (i < DEG + 1) ? 0.0f : t[i - (DEG + 1)];
}

// ---------------- weights: one thread per sample ----------------
__global__ __launch_bounds__(256) void weights_kernel(
    const float* __restrict__ t, const int* __restrict__ delta_p,
    float* __restrict__ out_pts, int* __restrict__ jbuf,
    vfloat4* __restrict__ bbuf, int S, int NK)
{
    int s = blockIdx.x * blockDim.x + threadIdx.x;
    if (s >= S) return;
    const float delta = (float)(*delta_p);
    const float sv = (float)s * delta;
    out_pts[s] = sv;

    // rightmost j in [DEG, NK+DEG-1] with kn(j) <= sv
    int lo = DEG, hi = NK + DEG - 1;
    while (lo < hi) {
        int mid = (lo + hi + 1) >> 1;
        if (kn(t, mid) <= sv) lo = mid; else hi = mid - 1;
    }
    const int j = lo;

    if (j >= NK) {  // beyond last degree-0 span: B row identically zero
        jbuf[s] = NK - 1;                    // valid addresses; b=0 zeroes output
        bbuf[s] = (vfloat4){0.f, 0.f, 0.f, 0.f};
        return;
    }

    // Cox-de Boor triangle: N[d][k] = val(j-d+k, d), where(denom==0 -> 0)
    float N[DEG + 1][DEG + 1];
    N[0][0] = 1.0f;
    #pragma unroll
    for (int d = 1; d <= DEG; ++d) {
        #pragma unroll
        for (int k = 0; k <= d; ++k) {
            int i = j - d + k;
            float vpi  = (k >= 1) ? N[d - 1][k - 1] : 0.0f;
            float vpi1 = (k <= d - 1) ? N[d - 1][k] : 0.0f;
            float ki   = kn(t, i);
            float kid  = kn(t, i + d);
            float ki1  = kn(t, i + 1);
            float kid1 = kn(t, i + d + 1);
            float den1 = kid - ki;
            float den2 = kid1 - ki1;
            float w1 = (den1 != 0.0f) ? (sv - ki) / den1 : 0.0f;
            float w2 = (den2 != 0.0f) ? (kid1 - sv) / den2 : 0.0f;
            N[d][k] = w1 * vpi + w2 * vpi1;
        }
    }

    // stale-column quirk: col i keeps degree min(DEG, NK-1-i)
    float b[DEG + 1];
    #pragma unroll
    for (int m = 0; m <= DEG; ++m) {
        int col = j - DEG + m;
        int deg = NK - 1 - col; if (deg > DEG) deg = DEG;
        int idx = m - DEG + deg;
        b[m] = (idx >= 0) ? N[deg][idx] : 0.0f;
    }
    jbuf[s] = j;
    bbuf[s] = (vfloat4){b[0], b[1], b[2], b[3]};
}

// ---------------- eval: wave = 8 samples x 64 float4-columns (half row) -----
// lane owns float4-column `col` (dims 4*col..4*col+3). Gathers c[dim][j-3..j]
// directly (no cT). All j/b wave-uniform -> scalar loads, uniform branches.
__global__ __launch_bounds__(256) void bspline_eval(
    const int* __restrict__ jbuf, const vfloat4* __restrict__ bbuf,
    const float* __restrict__ c, vfloat4* __restrict__ out_spline,
    int NK, int DIM)
{
    const int nvec = DIM >> 2;                       // 128
    int gtid = blockIdx.x * blockDim.x + threadIdx.x;
    int wid  = gtid >> 6;                            // global wave id
    int lane = gtid & 63;
    int grp  = wid >> 1;                             // 8-sample group
    int half = wid & 1;
    int s0   = __builtin_amdgcn_readfirstlane(grp << 3);
    int col  = (half << 6) | lane;                   // float4-column 0..127

    int j[8];
    vfloat4 b[8];
    #pragma unroll
    for (int m = 0; m < 8; ++m) { j[m] = jbuf[s0 + m]; b[m] = bbuf[s0 + m]; }

    const float* __restrict__ crow = c + (size_t)(4 * col) * NK;  // dim 4*col
    vfloat4* orow = out_spline + (size_t)s0 * nvec + col;

    vfloat4 o[8];

    if (j[0] == j[7]) {
        // whole group shares the span: 16 scalar loads -> 8 outputs
        #pragma unroll
        for (int k = 0; k < 4; ++k) {
            const float* p = crow + (size_t)k * NK + (j[0] - 3);
            float x0 = p[0], x1 = p[1], x2 = p[2], x3 = p[3];
            #pragma unroll
            for (int m = 0; m < 8; ++m)
                o[m][k] = b[m].x * x0 + b[m].y * x1 + b[m].z * x2 + b[m].w * x3;
        }
    } else {
        #pragma unroll
        for (int h = 0; h < 2; ++h) {
            const int m0 = h * 4;
            if (j[m0] == j[m0 + 3]) {
                #pragma unroll
                for (int k = 0; k < 4; ++k) {
                    const float* p = crow + (size_t)k * NK + (j[m0] - 3);
                    float x0 = p[0], x1 = p[1], x2 = p[2], x3 = p[3];
                    #pragma unroll
                    for (int m = m0; m < m0 + 4; ++m)
                        o[m][k] = b[m].x * x0 + b[m].y * x1 + b[m].z * x2 + b[m].w * x3;
                }
            } else {
                #pragma unroll
                for (int k = 0; k < 4; ++k) {
                    const float* p = crow + (size_t)k * NK;
                    #pragma unroll
                    for (int m = m0; m < m0 + 4; ++m) {
                        const float* q = p + (j[m] - 3);
                        o[m][k] = b[m].x * q[0] + b[m].y * q[1]
                                + b[m].z * q[2] + b[m].w * q[3];
                    }
                }
            }
        }
    }

    #pragma unroll
    for (int m = 0; m < 8; ++m)
        __builtin_nontemporal_store(o[m], orow + m * nvec);
}

extern "C" void kernel_launch(void* const* d_in, const int* in_sizes, int n_in,
                              void* d_out, int out_size, void* d_ws, size_t ws_size,
                              hipStream_t stream) {
    const float* t = (const float*)d_in[0];
    const float* c = (const float*)d_in[1];
    const int* delta = (const int*)d_in[2];
    const int NK = in_sizes[0];                 // 2048
    const int DIM = in_sizes[1] / NK;           // 512
    const int S = out_size / (1 + DIM);         // 32768

    int* jbuf = (int*)d_ws;                                    // S ints = 128 KB
    vfloat4* bbuf = (vfloat4*)((char*)d_ws + (size_t)S * 4);   // S vfloat4 = 512 KB

    weights_kernel<<<(S + 255) / 256, 256, 0, stream>>>(
        t, delta, (float*)d_out, jbuf, bbuf, S, NK);

    // 2 waves (halves) per 8-sample group: S/8 * 2 waves * 64 lanes
    int total_threads = (S >> 3) * 2 * 64;      // 524288 -> 2048 blocks
    bspline_eval<<<total_threads / 256, 256, 0, stream>>>(
        jbuf, bbuf, c, (vfloat4*)((float*)d_out + S), NK, DIM);
}

// Round 8
// 94.621 us; speedup vs baseline: 1.1321x; 1.1321x over previous
//
#include <hip/hip_runtime.h>

// BSpline evaluation, MI355X.
// t [2048] f32 sorted, c [512,2048] f32, delta [1] i32.
// out = sample_points [S] ++ spline_values [S, DIM]; S=32768, DIM=512.
// B rows have <=4 nonzeros (cols j-3..j, j = knot span), incl. the reference's
// stale-column quirk (col i final degree = min(3, NK-1-i)).
// R8 = R4 (best, 93.9us) + vectorized 64x64 float4 transpose in prep.
// Journal: R6 fuse-weights-into-eval 97.1 (search on critical path);
// R7 no-transpose gather 107.1 (64 cache lines per load inst). Eval is
// store-bound (~67 MB NT writes); load-halving (R5) was neutral.

#define DEG 3

typedef float vfloat4 __attribute__((ext_vector_type(4)));

__device__ __forceinline__ float kn(const float* __restrict__ t, int i) {
    return (i < DEG + 1) ? 0.0f : t[i - (DEG + 1)];
}

// ---------------- fused prep ----------------
// blocks [0, TB): transpose c [DIM][NK] -> cT [NK][DIM], 64x64 float4 tiles
// blocks [TB, TB+WB): weights (span search + Cox-de Boor triangle per sample)
__global__ __launch_bounds__(256) void prep_kernel(
    const float* __restrict__ c, float* __restrict__ cT,
    const float* __restrict__ t, const int* __restrict__ delta_p,
    float* __restrict__ out_pts, int* __restrict__ jbuf,
    vfloat4* __restrict__ bbuf, int S, int NK, int DIM, int TB)
{
    if ((int)blockIdx.x < TB) {
        // ---- 64x64 tile transpose, float4 both directions ----
        __shared__ float tile[64][65];
        const int ntx = NK / 64;             // tiles along NK (32)
        int bx = blockIdx.x % ntx;           // tile col in c (NK dir)
        int by = blockIdx.x / ntx;           // tile row in c (DIM dir)
        int c4 = threadIdx.x & 15;           // float4 column within tile
        int r0 = threadIdx.x >> 4;           // 0..15
        #pragma unroll
        for (int rr = 0; rr < 4; ++rr) {
            int r = r0 + rr * 16;
            vfloat4 v = *(const vfloat4*)(c + (size_t)(by * 64 + r) * NK + bx * 64 + c4 * 4);
            tile[r][c4 * 4 + 0] = v.x;
            tile[r][c4 * 4 + 1] = v.y;
            tile[r][c4 * 4 + 2] = v.z;
            tile[r][c4 * 4 + 3] = v.w;
        }
        __syncthreads();
        #pragma unroll
        for (int rr = 0; rr < 4; ++rr) {
            int r = r0 + rr * 16;            // row in cT tile (NK dir)
            vfloat4 v;
            v.x = tile[c4 * 4 + 0][r];
            v.y = tile[c4 * 4 + 1][r];
            v.z = tile[c4 * 4 + 2][r];
            v.w = tile[c4 * 4 + 3][r];
            *(vfloat4*)(cT + (size_t)(bx * 64 + r) * DIM + by * 64 + c4 * 4) = v;
        }
        return;
    }

    // ---- weights part: one thread per sample ----
    int s = (blockIdx.x - TB) * blockDim.x + threadIdx.x;
    if (s >= S) return;
    const float delta = (float)(*delta_p);
    const float sv = (float)s * delta;
    out_pts[s] = sv;

    // rightmost j in [DEG, NK+DEG-1] with kn(j) <= sv
    int lo = DEG, hi = NK + DEG - 1;
    while (lo < hi) {
        int mid = (lo + hi + 1) >> 1;
        if (kn(t, mid) <= sv) lo = mid; else hi = mid - 1;
    }
    const int j = lo;

    if (j >= NK) {  // beyond last degree-0 span: B row identically zero
        jbuf[s] = NK - 1;                    // valid addresses; b=0 zeroes output
        bbuf[s] = (vfloat4){0.f, 0.f, 0.f, 0.f};
        return;
    }

    // Cox-de Boor triangle: N[d][k] = val(j-d+k, d), where(denom==0 -> 0)
    float N[DEG + 1][DEG + 1];
    N[0][0] = 1.0f;
    #pragma unroll
    for (int d = 1; d <= DEG; ++d) {
        #pragma unroll
        for (int k = 0; k <= d; ++k) {
            int i = j - d + k;
            float vpi  = (k >= 1) ? N[d - 1][k - 1] : 0.0f;
            float vpi1 = (k <= d - 1) ? N[d - 1][k] : 0.0f;
            float ki   = kn(t, i);
            float kid  = kn(t, i + d);
            float ki1  = kn(t, i + 1);
            float kid1 = kn(t, i + d + 1);
            float den1 = kid - ki;
            float den2 = kid1 - ki1;
            float w1 = (den1 != 0.0f) ? (sv - ki) / den1 : 0.0f;
            float w2 = (den2 != 0.0f) ? (kid1 - sv) / den2 : 0.0f;
            N[d][k] = w1 * vpi + w2 * vpi1;
        }
    }

    // stale-column quirk: col i keeps degree min(DEG, NK-1-i)
    float b[DEG + 1];
    #pragma unroll
    for (int m = 0; m <= DEG; ++m) {
        int col = j - DEG + m;
        int deg = NK - 1 - col; if (deg > DEG) deg = DEG;
        int idx = m - DEG + deg;
        b[m] = (idx >= 0) ? N[deg][idx] : 0.0f;
    }
    jbuf[s] = j;
    bbuf[s] = (vfloat4){b[0], b[1], b[2], b[3]};
}

// ---------------- streaming eval: 4 consecutive samples per thread ----------
// Wave = sample-group s0..s0+3 x 64 of 128 float4 row-lanes; j/b wave-uniform
// scalar loads; span branch uniform. Fast path (j0==j3, ~78%): 4 loads->4 outs.
__device__ __forceinline__ vfloat4 dot4(const vfloat4 b, const vfloat4 a0,
                                        const vfloat4 a1, const vfloat4 a2,
                                        const vfloat4 a3) {
    return b.x * a0 + b.y * a1 + b.z * a2 + b.w * a3;
}

__global__ __launch_bounds__(256) void bspline_eval(
    const int* __restrict__ jbuf, const vfloat4* __restrict__ bbuf,
    const float* __restrict__ cT, vfloat4* __restrict__ out_spline,
    int DIM)
{
    const int nvec = DIM >> 2;                    // 128
    int gtid = blockIdx.x * blockDim.x + threadIdx.x;
    int wid  = gtid >> 6;
    int lane = gtid & 63;
    int grp  = wid >> 1;                          // sample group (wave-uniform)
    int d    = ((wid & 1) << 6) | lane;           // 0..127
    int s0   = __builtin_amdgcn_readfirstlane(grp << 2);

    const int j0 = jbuf[s0 + 0];
    const int j3 = jbuf[s0 + 3];
    const vfloat4 b0 = bbuf[s0 + 0];
    const vfloat4 b1 = bbuf[s0 + 1];
    const vfloat4 b2 = bbuf[s0 + 2];
    const vfloat4 b3 = bbuf[s0 + 3];

    vfloat4* o = out_spline + (size_t)s0 * nvec + d;

    if (j0 == j3) {
        const vfloat4* r = (const vfloat4*)(cT + (size_t)(j3 - 3) * DIM) + d;
        vfloat4 a0 = r[0];
        vfloat4 a1 = r[nvec];
        vfloat4 a2 = r[2 * nvec];
        vfloat4 a3 = r[3 * nvec];
        __builtin_nontemporal_store(dot4(b0, a0, a1, a2, a3), o);
        __builtin_nontemporal_store(dot4(b1, a0, a1, a2, a3), o + nvec);
        __builtin_nontemporal_store(dot4(b2, a0, a1, a2, a3), o + 2 * nvec);
        __builtin_nontemporal_store(dot4(b3, a0, a1, a2, a3), o + 3 * nvec);
    } else {
        const int j1 = jbuf[s0 + 1];
        const int j2 = jbuf[s0 + 2];
        const int js[4] = {j0, j1, j2, j3};
        const vfloat4 bs[4] = {b0, b1, b2, b3};
        #pragma unroll
        for (int m = 0; m < 4; ++m) {
            const vfloat4* r = (const vfloat4*)(cT + (size_t)(js[m] - 3) * DIM) + d;
            vfloat4 a0 = r[0];
            vfloat4 a1 = r[nvec];
            vfloat4 a2 = r[2 * nvec];
            vfloat4 a3 = r[3 * nvec];
            __builtin_nontemporal_store(dot4(bs[m], a0, a1, a2, a3), o + m * nvec);
        }
    }
}

extern "C" void kernel_launch(void* const* d_in, const int* in_sizes, int n_in,
                              void* d_out, int out_size, void* d_ws, size_t ws_size,
                              hipStream_t stream) {
    const float* t = (const float*)d_in[0];
    const float* c = (const float*)d_in[1];
    const int* delta = (const int*)d_in[2];
    const int NK = in_sizes[0];                 // 2048
    const int DIM = in_sizes[1] / NK;           // 512
    const int S = out_size / (1 + DIM);         // 32768

    float* cT = (float*)d_ws;                                  // NK*DIM f32 = 4 MB
    int* jbuf = (int*)((char*)d_ws + (size_t)NK * DIM * 4);    // S ints
    vfloat4* bbuf = (vfloat4*)((char*)jbuf + (size_t)S * 4);   // S vfloat4

    const int TB = (NK / 64) * (DIM / 64);      // 32*8 = 256 transpose blocks
    const int WB = (S + 255) / 256;             // 128 weights blocks
    prep_kernel<<<TB + WB, 256, 0, stream>>>(
        c, cT, t, delta, (float*)d_out, jbuf, bbuf, S, NK, DIM, TB);

    // 4 samples/thread, 2 waves per sample-group
    int total_threads = (S >> 2) * (DIM >> 2);  // 1.048M -> 4096 blocks
    bspline_eval<<<total_threads / 256, 256, 0, stream>>>(
        jbuf, bbuf, cT, (vfloat4*)((float*)d_out + S), DIM);
}